// Round 3
// baseline (136.273 us; speedup 1.0000x reference)
//
#include <hip/hip_runtime.h>
#include <hip/hip_bf16.h>

// NT-Xent loss, fused flash-LSE over sim = z z^T / T, bf16 MFMA.
// z = concat(z_i, z_j): [8192][128], pre-scaled by sqrt(log2e/T) so MFMA
// output is directly in log2 units. Per wave: 64 rows in registers (4 groups
// of 16), cols streamed through LDS chunks of 64 via global_load_lds DMA.
// Branchless deferred-max online LSE: m' = max(m, v...); s *= 2^(m-m'); then
// s += 2^(v-m') (diag's -inf contributes exp2(-inf)=0 automatically).

#define N_TOT 8192
#define B_HALF 4096
#define DIM 128
#define SPLITS 32
#define ROW_BLOCKS 32
#define ROWS_PER_BLOCK 256                 // 4 waves * 64 rows
#define COLS_PER_SPLIT 256
#define CHUNK 64
#define NCHUNK (COLS_PER_SPLIT / CHUNK)    // 4
#define PRESCALE 4.5398159686f             // sqrt(log2(e)/0.07)
#define LN2F 0.6931471805599453f

typedef __attribute__((ext_vector_type(8))) short bf16x8;
typedef __attribute__((ext_vector_type(4))) float f32x4;

__device__ __forceinline__ unsigned short f2bf_rne(float f) {
    unsigned int u = __float_as_uint(f);
    u += 0x7FFFu + ((u >> 16) & 1u);
    return (unsigned short)(u >> 16);
}

__device__ __forceinline__ void gload16(const void* g, void* l) {
    __builtin_amdgcn_global_load_lds(
        (const __attribute__((address_space(1))) unsigned int*)g,
        (__attribute__((address_space(3))) unsigned int*)l, 16, 0, 0);
}

// ---- kernel 1: convert z_i,z_j f32 -> pre-scaled bf16 z [8192][128] ----
__global__ void convert_kernel(const float* __restrict__ zi,
                               const float* __restrict__ zj,
                               unsigned short* __restrict__ z) {
    int t = blockIdx.x * 256 + threadIdx.x;
    int idx = t * 4;
    const float* src = (idx < B_HALF * DIM) ? (zi + idx) : (zj + (idx - B_HALF * DIM));
    float4 v = *(const float4*)src;
    ushort4 o;
    o.x = f2bf_rne(v.x * PRESCALE);
    o.y = f2bf_rne(v.y * PRESCALE);
    o.z = f2bf_rne(v.z * PRESCALE);
    o.w = f2bf_rne(v.w * PRESCALE);
    *(ushort4*)(z + idx) = o;
}

// ---- kernel 2: main fused GEMM + online LSE ----
// grid: 32 row-blocks (256 rows) * 32 col-splits (256 cols). 256 thr (4 waves).
__global__ __launch_bounds__(256, 4) void ntxent_main(
        const unsigned short* __restrict__ z,
        float* __restrict__ Wm, float* __restrict__ Ws, float* __restrict__ Wp) {
    // chunk buffer: slot = cs*256 + ks*64 + hi*16 + lo (16B units)
    // slot holds z[cbase + cs*16 + lo][k elems (ks*4+hi)*8 .. +8]
    __shared__ bf16x8 lds[2][1024]; // 2 x 16 KB

    const int bid = blockIdx.x;
    const int rb = bid / SPLITS;
    const int sb = bid % SPLITS;
    const int tid = threadIdx.x;
    const int w = tid >> 6;   // wave 0..3
    const int l = tid & 63;
    const int lo = l & 15;
    const int hi = l >> 4;

    const int rowbase = rb * ROWS_PER_BLOCK + w * 64;
    const int cbase0 = sb * COLS_PER_SPLIT;

    // wave w stages cs-group w: col = cbase + w*16 + lo, call j: k-chunk j*4+hi
    const unsigned short* gp = z + (size_t)(cbase0 + w * 16 + lo) * DIM + hi * 8;

    // prologue: stage chunk 0 into buffer 0
#pragma unroll
    for (int j = 0; j < 4; ++j)
        gload16(gp + j * 32, &lds[0][w * 256 + j * 64]);

    // row fragments: 64 rows per wave, 4 groups of 16, K=128
    bf16x8 bfrag[4][4];
#pragma unroll
    for (int rg = 0; rg < 4; ++rg) {
        const unsigned short* zr = z + (size_t)(rowbase + rg * 16 + lo) * DIM + hi * 8;
#pragma unroll
        for (int ks = 0; ks < 4; ++ks)
            bfrag[rg][ks] = *(const bf16x8*)(zr + ks * 32);
    }

    float m[4], s[4], pos[4];
#pragma unroll
    for (int rg = 0; rg < 4; ++rg) { m[rg] = -INFINITY; s[rg] = 0.f; pos[rg] = -INFINITY; }

    const int dchunk = rowbase >> 6;            // wave's 64 rows: diag col-chunk
    const int pchunk = dchunk ^ (B_HALF >> 6);  // partner col-chunk

    asm volatile("s_waitcnt vmcnt(0)" ::: "memory");
    __syncthreads();

    for (int c = 0; c < NCHUNK; ++c) {
        if (c + 1 < NCHUNK) {
            gp += CHUNK * DIM;
#pragma unroll
            for (int j = 0; j < 4; ++j)
                gload16(gp + j * 32, &lds[(c + 1) & 1][w * 256 + j * 64]);
        }
        const bf16x8* buf = lds[c & 1];
        const int cb = cbase0 + c * CHUNK;
        const bool check = ((cb >> 6) == dchunk) || ((cb >> 6) == pchunk);

#pragma unroll
        for (int cs = 0; cs < 4; ++cs) {
            bf16x8 a0 = buf[cs * 256 + 0 * 64 + l];
            bf16x8 a1 = buf[cs * 256 + 1 * 64 + l];
            bf16x8 a2 = buf[cs * 256 + 2 * 64 + l];
            bf16x8 a3 = buf[cs * 256 + 3 * 64 + l];
            f32x4 acc[4];
#pragma unroll
            for (int rg = 0; rg < 4; ++rg) acc[rg] = (f32x4){0.f, 0.f, 0.f, 0.f};
#pragma unroll
            for (int rg = 0; rg < 4; ++rg) {
                acc[rg] = __builtin_amdgcn_mfma_f32_16x16x32_bf16(a0, bfrag[rg][0], acc[rg], 0, 0, 0);
                acc[rg] = __builtin_amdgcn_mfma_f32_16x16x32_bf16(a1, bfrag[rg][1], acc[rg], 0, 0, 0);
                acc[rg] = __builtin_amdgcn_mfma_f32_16x16x32_bf16(a2, bfrag[rg][2], acc[rg], 0, 0, 0);
                acc[rg] = __builtin_amdgcn_mfma_f32_16x16x32_bf16(a3, bfrag[rg][3], acc[rg], 0, 0, 0);
            }

            const int c0 = cb + cs * 16 + hi * 4;
#pragma unroll
            for (int rg = 0; rg < 4; ++rg) {
                float v0 = acc[rg][0], v1 = acc[rg][1], v2 = acc[rg][2], v3 = acc[rg][3];
                if (check) {
                    int r = rowbase + rg * 16 + lo;
                    int p = r ^ B_HALF;
                    if (c0 + 0 == r) v0 = -INFINITY; else if (c0 + 0 == p) pos[rg] = v0;
                    if (c0 + 1 == r) v1 = -INFINITY; else if (c0 + 1 == p) pos[rg] = v1;
                    if (c0 + 2 == r) v2 = -INFINITY; else if (c0 + 2 == p) pos[rg] = v2;
                    if (c0 + 3 == r) v3 = -INFINITY; else if (c0 + 3 == p) pos[rg] = v3;
                }
                // branchless deferred-max online LSE (exact):
                float mn = fmaxf(fmaxf(m[rg], v0), fmaxf(v1, fmaxf(v2, v3)));
                s[rg] *= __builtin_amdgcn_exp2f(m[rg] - mn);  // exp2(0)=1 no-op
                m[rg] = mn;
                float e0 = __builtin_amdgcn_exp2f(v0 - mn);
                float e1 = __builtin_amdgcn_exp2f(v1 - mn);
                float e2 = __builtin_amdgcn_exp2f(v2 - mn);
                float e3 = __builtin_amdgcn_exp2f(v3 - mn);
                s[rg] += (e0 + e1) + (e2 + e3);
            }
        }
        asm volatile("s_waitcnt vmcnt(0)" ::: "memory");
        __syncthreads();
    }

    // merge 4 partner lanes (same row, hi=0..3): xor 16 then 32
#pragma unroll
    for (int rg = 0; rg < 4; ++rg) {
        float mm = m[rg], ss = s[rg], pp = pos[rg];
#pragma unroll
        for (int off = 16; off <= 32; off <<= 1) {
            float m2 = __shfl_xor(mm, off);
            float s2 = __shfl_xor(ss, off);
            float p2 = __shfl_xor(pp, off);
            float M = fmaxf(mm, m2);
            ss = ss * __builtin_amdgcn_exp2f(mm - M) + s2 * __builtin_amdgcn_exp2f(m2 - M);
            mm = M;
            pp = fmaxf(pp, p2);
        }
        if (hi == 0) {
            int r = rowbase + rg * 16 + lo;
            Wm[sb * N_TOT + r] = mm;
            Ws[sb * N_TOT + r] = ss;
            Wp[sb * N_TOT + r] = pp;
        }
    }
}

// ---- kernel 3: merge splits, compute loss, reduce ----
__global__ void merge_kernel(const float* __restrict__ Wm,
                             const float* __restrict__ Ws,
                             const float* __restrict__ Wp,
                             float* __restrict__ out) {
    int r = blockIdx.x * 256 + threadIdx.x; // 0..8191
    float m = -INFINITY, s = 0.f, p = -INFINITY;
#pragma unroll
    for (int sb = 0; sb < SPLITS; ++sb) {
        float m2 = Wm[sb * N_TOT + r];
        float s2 = Ws[sb * N_TOT + r];
        float p2 = Wp[sb * N_TOT + r];
        float M = fmaxf(m, m2);
        s = s * __builtin_amdgcn_exp2f(m - M) + s2 * __builtin_amdgcn_exp2f(m2 - M);
        m = M;
        p = fmaxf(p, p2);
    }
    // aug row = [pos, neg-row]: add exp(pos) once more
    s += __builtin_amdgcn_exp2f(p - m);
    float loss = ((m + __builtin_amdgcn_logf(s)) - p) * LN2F;

#pragma unroll
    for (int off = 32; off >= 1; off >>= 1)
        loss += __shfl_down(loss, off);
    __shared__ float wsum[4];
    if ((threadIdx.x & 63) == 0) wsum[threadIdx.x >> 6] = loss;
    __syncthreads();
    if (threadIdx.x == 0) {
        float t = wsum[0] + wsum[1] + wsum[2] + wsum[3];
        atomicAdd(out, t * (1.0f / (float)N_TOT));
    }
}

extern "C" void kernel_launch(void* const* d_in, const int* in_sizes, int n_in,
                              void* d_out, int out_size, void* d_ws, size_t ws_size,
                              hipStream_t stream) {
    const float* zi = (const float*)d_in[0];
    const float* zj = (const float*)d_in[1];
    float* out = (float*)d_out;

    unsigned short* z = (unsigned short*)d_ws;                 // 2 MB
    float* Wm = (float*)((char*)d_ws + N_TOT * DIM * 2);
    float* Ws = Wm + SPLITS * N_TOT;
    float* Wp = Ws + SPLITS * N_TOT;

    hipMemsetAsync(d_out, 0, sizeof(float), stream);
    convert_kernel<<<(N_TOT * DIM / 4) / 256, 256, 0, stream>>>(zi, zj, z);
    ntxent_main<<<ROW_BLOCKS * SPLITS, 256, 0, stream>>>(z, Wm, Ws, Wp);
    merge_kernel<<<N_TOT / 256, 256, 0, stream>>>(Wm, Ws, Wp, out);
}

// Round 4
// 92.839 us; speedup vs baseline: 1.4679x; 1.4679x over previous
//
#include <hip/hip_runtime.h>
#include <hip/hip_bf16.h>

// NT-Xent loss, fused flash-LSE over sim = z z^T / T, bf16 32x32x16 MFMA.
// z = concat(z_i, z_j): [8192][128] bf16, pre-scaled by sqrt(log2e/T) so the
// MFMA output is directly in log2 units. sim is symmetric, so A (stream cols)
// and B (owned rows) fragments have IDENTICAL layouts from row-major z:
// no LDS, no barriers — each wave loads A-frags straight from L2 (z = 2 MB,
// resident in every XCD's L2; 8KB/tile reused from L1 across k-steps).
// Wave: 64 rows (2 B-tiles of 32), sweeps 256 cols in 8 tiles of 32.
// C layout (32x32): col = lane&31 = our row -> per-lane LSE state is 2 rows.

#define N_TOT 8192
#define B_HALF 4096
#define DIM 128
#define SPLITS 32
#define COLS_PER_SPLIT 256
#define NTILE 8                            // 256 / 32
#define PRESCALE 4.5398159686f             // sqrt(log2(e)/0.07)
#define LN2F 0.6931471805599453f

typedef __attribute__((ext_vector_type(8))) short bf16x8;
typedef __attribute__((ext_vector_type(16))) float f32x16;

__device__ __forceinline__ unsigned short f2bf_rne(float f) {
    unsigned int u = __float_as_uint(f);
    u += 0x7FFFu + ((u >> 16) & 1u);
    return (unsigned short)(u >> 16);
}

// ---- kernel 1: convert z_i,z_j f32 -> pre-scaled bf16 z [8192][128] ----
__global__ void convert_kernel(const float* __restrict__ zi,
                               const float* __restrict__ zj,
                               unsigned short* __restrict__ z) {
    int t = blockIdx.x * 256 + threadIdx.x;
    int idx = t * 4;
    const float* src = (idx < B_HALF * DIM) ? (zi + idx) : (zj + (idx - B_HALF * DIM));
    float4 v = *(const float4*)src;
    ushort4 o;
    o.x = f2bf_rne(v.x * PRESCALE);
    o.y = f2bf_rne(v.y * PRESCALE);
    o.z = f2bf_rne(v.z * PRESCALE);
    o.w = f2bf_rne(v.w * PRESCALE);
    *(ushort4*)(z + idx) = o;
}

// ---- kernel 2: main fused GEMM + online LSE (no LDS, no barriers) ----
// 4096 independent waves: 128 row-waves (64 rows) x 32 col-splits (256 cols).
// 1024 blocks x 256 threads; block's 4 waves share a col-split (L1 reuse).
__global__ __launch_bounds__(256, 2) void ntxent_main(
        const unsigned short* __restrict__ z,
        float* __restrict__ Wm, float* __restrict__ Ws, float* __restrict__ Wp) {
    const int tid = threadIdx.x;
    const int wid = blockIdx.x * 4 + (tid >> 6);
    const int sp = wid >> 7;        // col-split 0..31
    const int rw = wid & 127;       // row-wave 0..127
    const int l = tid & 63;
    const int l5 = l & 31;
    const int hb = l >> 5;          // k-half select

    const int rowbase = rw * 64;
    const int cb0 = sp * COLS_PER_SPLIT;
    const int row0[2] = {rowbase, rowbase + 32};

    // B fragments: 64 owned rows as two 32-row tiles, K=128 in 8 k-steps.
    // layout: lane holds z[row0[rt] + (l&31)][(l>>5)*8 + 16*ks .. +8]
    bf16x8 bf[2][8];
#pragma unroll
    for (int rt = 0; rt < 2; ++rt) {
        const unsigned short* bp = z + (size_t)(row0[rt] + l5) * DIM + hb * 8;
#pragma unroll
        for (int ks = 0; ks < 8; ++ks)
            bf[rt][ks] = *(const bf16x8*)(bp + ks * 16);
    }

    // A fragments: same layout over stream cols, double-buffered in regs.
    const unsigned short* ap = z + (size_t)(cb0 + l5) * DIM + hb * 8;

    float m[2] = {-INFINITY, -INFINITY};
    float s[2] = {0.f, 0.f};
    float pos[2] = {-INFINITY, -INFINITY};

    bf16x8 a[2][8];
#pragma unroll
    for (int ks = 0; ks < 8; ++ks)
        a[0][ks] = *(const bf16x8*)(ap + ks * 16);

#pragma unroll
    for (int ct = 0; ct < NTILE; ++ct) {
        const int cur = ct & 1;             // static after full unroll
        if (ct + 1 < NTILE) {
            const unsigned short* an = ap + (size_t)(ct + 1) * 32 * DIM;
#pragma unroll
            for (int ks = 0; ks < 8; ++ks)
                a[cur ^ 1][ks] = *(const bf16x8*)(an + ks * 16);
        }

        f32x16 acc0, acc1;
#pragma unroll
        for (int q = 0; q < 16; ++q) { acc0[q] = 0.f; acc1[q] = 0.f; }
#pragma unroll
        for (int ks = 0; ks < 8; ++ks) {
            acc0 = __builtin_amdgcn_mfma_f32_32x32x16_bf16(a[cur][ks], bf[0][ks], acc0, 0, 0, 0);
            acc1 = __builtin_amdgcn_mfma_f32_32x32x16_bf16(a[cur][ks], bf[1][ks], acc1, 0, 0, 0);
        }

        const int cb = cb0 + ct * 32;
#pragma unroll
        for (int rt = 0; rt < 2; ++rt) {
            f32x16 acc = rt ? acc1 : acc0;  // static select post-unroll
            const int j = row0[rt] + l5;    // this lane's row
            // diag / partner windows are 32-aligned: wave-uniform check
            const bool check = (cb == row0[rt]) || (cb == (row0[rt] ^ B_HALF));
            if (check) {
#pragma unroll
                for (int q = 0; q < 16; ++q) {
                    int iq = cb + (q & 3) + 8 * (q >> 2) + 4 * hb; // stream col
                    if (iq == j) acc[q] = -INFINITY;
                    else if (iq == (j ^ B_HALF)) pos[rt] = acc[q];
                }
            }
            // branchless deferred-max online LSE over 16 values
            float x0 = fmaxf(acc[0], acc[1]),   x1 = fmaxf(acc[2], acc[3]);
            float x2 = fmaxf(acc[4], acc[5]),   x3 = fmaxf(acc[6], acc[7]);
            float x4 = fmaxf(acc[8], acc[9]),   x5 = fmaxf(acc[10], acc[11]);
            float x6 = fmaxf(acc[12], acc[13]), x7 = fmaxf(acc[14], acc[15]);
            float y0 = fmaxf(x0, x1), y1 = fmaxf(x2, x3);
            float y2 = fmaxf(x4, x5), y3 = fmaxf(x6, x7);
            float tmax = fmaxf(fmaxf(y0, y1), fmaxf(y2, y3));
            float mn = fmaxf(m[rt], tmax);
            float r = __builtin_amdgcn_exp2f(m[rt] - mn);   // exp2(0)=1 no-op
            float e0 = __builtin_amdgcn_exp2f(acc[0] - mn);
            float e1 = __builtin_amdgcn_exp2f(acc[1] - mn);
            float e2 = __builtin_amdgcn_exp2f(acc[2] - mn);
            float e3 = __builtin_amdgcn_exp2f(acc[3] - mn);
            float e4 = __builtin_amdgcn_exp2f(acc[4] - mn);
            float e5 = __builtin_amdgcn_exp2f(acc[5] - mn);
            float e6 = __builtin_amdgcn_exp2f(acc[6] - mn);
            float e7 = __builtin_amdgcn_exp2f(acc[7] - mn);
            float e8 = __builtin_amdgcn_exp2f(acc[8] - mn);
            float e9 = __builtin_amdgcn_exp2f(acc[9] - mn);
            float ea = __builtin_amdgcn_exp2f(acc[10] - mn);
            float eb = __builtin_amdgcn_exp2f(acc[11] - mn);
            float ec = __builtin_amdgcn_exp2f(acc[12] - mn);
            float ed = __builtin_amdgcn_exp2f(acc[13] - mn);
            float ee = __builtin_amdgcn_exp2f(acc[14] - mn);
            float ef = __builtin_amdgcn_exp2f(acc[15] - mn);
            float t0 = (e0 + e1) + (e2 + e3);
            float t1 = (e4 + e5) + (e6 + e7);
            float t2 = (e8 + e9) + (ea + eb);
            float t3 = (ec + ed) + (ee + ef);
            s[rt] = s[rt] * r + ((t0 + t1) + (t2 + t3));
            m[rt] = mn;
        }
    }

    // lanes l and l^32 hold the same rows (disjoint stream-col subsets): merge
#pragma unroll
    for (int rt = 0; rt < 2; ++rt) {
        float mm = m[rt], ss = s[rt], pp = pos[rt];
        float m2 = __shfl_xor(mm, 32);
        float s2 = __shfl_xor(ss, 32);
        float p2 = __shfl_xor(pp, 32);
        float M = fmaxf(mm, m2);
        ss = ss * __builtin_amdgcn_exp2f(mm - M) + s2 * __builtin_amdgcn_exp2f(m2 - M);
        pp = fmaxf(pp, p2);
        if (l < 32) {
            int r = row0[rt] + l;
            Wm[sp * N_TOT + r] = M;
            Ws[sp * N_TOT + r] = ss;
            Wp[sp * N_TOT + r] = pp;
        }
    }
}

// ---- kernel 3: merge splits, compute loss, reduce ----
__global__ void merge_kernel(const float* __restrict__ Wm,
                             const float* __restrict__ Ws,
                             const float* __restrict__ Wp,
                             float* __restrict__ out) {
    int r = blockIdx.x * 256 + threadIdx.x; // 0..8191
    float m = -INFINITY, s = 0.f, p = -INFINITY;
#pragma unroll
    for (int sb = 0; sb < SPLITS; ++sb) {
        float m2 = Wm[sb * N_TOT + r];
        float s2 = Ws[sb * N_TOT + r];
        float p2 = Wp[sb * N_TOT + r];
        float M = fmaxf(m, m2);
        s = s * __builtin_amdgcn_exp2f(m - M) + s2 * __builtin_amdgcn_exp2f(m2 - M);
        m = M;
        p = fmaxf(p, p2);
    }
    // aug row = [pos, neg-row]: add exp(pos) once more
    s += __builtin_amdgcn_exp2f(p - m);
    float loss = ((m + __builtin_amdgcn_logf(s)) - p) * LN2F;

#pragma unroll
    for (int off = 32; off >= 1; off >>= 1)
        loss += __shfl_down(loss, off);
    __shared__ float wsum[4];
    if ((threadIdx.x & 63) == 0) wsum[threadIdx.x >> 6] = loss;
    __syncthreads();
    if (threadIdx.x == 0) {
        float t = wsum[0] + wsum[1] + wsum[2] + wsum[3];
        atomicAdd(out, t * (1.0f / (float)N_TOT));
    }
}

extern "C" void kernel_launch(void* const* d_in, const int* in_sizes, int n_in,
                              void* d_out, int out_size, void* d_ws, size_t ws_size,
                              hipStream_t stream) {
    const float* zi = (const float*)d_in[0];
    const float* zj = (const float*)d_in[1];
    float* out = (float*)d_out;

    unsigned short* z = (unsigned short*)d_ws;                 // 2 MB
    float* Wm = (float*)((char*)d_ws + N_TOT * DIM * 2);
    float* Ws = Wm + SPLITS * N_TOT;
    float* Wp = Ws + SPLITS * N_TOT;

    hipMemsetAsync(d_out, 0, sizeof(float), stream);
    convert_kernel<<<(N_TOT * DIM / 4) / 256, 256, 0, stream>>>(zi, zj, z);
    ntxent_main<<<(128 * SPLITS) / 4, 256, 0, stream>>>(z, Wm, Ws, Wp);
    merge_kernel<<<N_TOT / 256, 256, 0, stream>>>(Wm, Ws, Wp, out);
}

// Round 5
// 78.689 us; speedup vs baseline: 1.7318x; 1.1798x over previous
//
#include <hip/hip_runtime.h>
#include <hip/hip_bf16.h>

// NT-Xent loss, fused flash-LSE over sim = z z^T / T, bf16 32x32x16 MFMA.
// z = concat(z_i, z_j): [8192][128] bf16, pre-scaled by sqrt(log2e/T) so the
// MFMA output is directly in log2 units. sim is symmetric: A (stream cols)
// and B (owned rows) fragments have IDENTICAL layouts from row-major z ->
// no LDS, no barriers; waves load A straight from L2 (z = 2 MB, L2-resident).
// Wave: 32 rows (one B-tile), sweeps 512 cols as 16 tiles of 32, A in two
// NAMED reg buffers ping-ponged by an explicitly 2x-unrolled pair loop
// (no runtime-indexed register arrays -> no scratch).
// C layout (32x32): col = lane&31 = owned row -> lane's LSE state is 1 row.

#define N_TOT 8192
#define B_HALF 4096
#define DIM 128
#define SPLITS 16
#define COLS_PER_SPLIT 512
#define NTILE 16                           // 512 / 32
#define PRESCALE 4.5398159686f             // sqrt(log2(e)/0.07)
#define LN2F 0.6931471805599453f

typedef __attribute__((ext_vector_type(8))) short bf16x8;
typedef __attribute__((ext_vector_type(16))) float f32x16;

__device__ __forceinline__ unsigned short f2bf_rne(float f) {
    unsigned int u = __float_as_uint(f);
    u += 0x7FFFu + ((u >> 16) & 1u);
    return (unsigned short)(u >> 16);
}

// ---- kernel 1: convert z_i,z_j f32 -> pre-scaled bf16 z [8192][128] ----
__global__ void convert_kernel(const float* __restrict__ zi,
                               const float* __restrict__ zj,
                               unsigned short* __restrict__ z) {
    int t = blockIdx.x * 256 + threadIdx.x;
    int idx = t * 4;
    const float* src = (idx < B_HALF * DIM) ? (zi + idx) : (zj + (idx - B_HALF * DIM));
    float4 v = *(const float4*)src;
    ushort4 o;
    o.x = f2bf_rne(v.x * PRESCALE);
    o.y = f2bf_rne(v.y * PRESCALE);
    o.z = f2bf_rne(v.z * PRESCALE);
    o.w = f2bf_rne(v.w * PRESCALE);
    *(ushort4*)(z + idx) = o;
}

// load one 32-col A-tile (8 k-step fragments) into 8 named regs
#define LOAD_A(buf, p)                                                         \
    do {                                                                       \
        buf##0 = *(const bf16x8*)((p) + 0 * 16);                               \
        buf##1 = *(const bf16x8*)((p) + 1 * 16);                               \
        buf##2 = *(const bf16x8*)((p) + 2 * 16);                               \
        buf##3 = *(const bf16x8*)((p) + 3 * 16);                               \
        buf##4 = *(const bf16x8*)((p) + 4 * 16);                               \
        buf##5 = *(const bf16x8*)((p) + 5 * 16);                               \
        buf##6 = *(const bf16x8*)((p) + 6 * 16);                               \
        buf##7 = *(const bf16x8*)((p) + 7 * 16);                               \
    } while (0)

#define MFMA8(buf)                                                             \
    do {                                                                       \
        acc = __builtin_amdgcn_mfma_f32_32x32x16_bf16(buf##0, b0, acc, 0, 0, 0); \
        acc = __builtin_amdgcn_mfma_f32_32x32x16_bf16(buf##1, b1, acc, 0, 0, 0); \
        acc = __builtin_amdgcn_mfma_f32_32x32x16_bf16(buf##2, b2, acc, 0, 0, 0); \
        acc = __builtin_amdgcn_mfma_f32_32x32x16_bf16(buf##3, b3, acc, 0, 0, 0); \
        acc = __builtin_amdgcn_mfma_f32_32x32x16_bf16(buf##4, b4, acc, 0, 0, 0); \
        acc = __builtin_amdgcn_mfma_f32_32x32x16_bf16(buf##5, b5, acc, 0, 0, 0); \
        acc = __builtin_amdgcn_mfma_f32_32x32x16_bf16(buf##6, b6, acc, 0, 0, 0); \
        acc = __builtin_amdgcn_mfma_f32_32x32x16_bf16(buf##7, b7, acc, 0, 0, 0); \
    } while (0)

// consume one 32x32 result tile at stream-col base `cb` into (m,s,pos)
#define CONSUME(cb)                                                            \
    do {                                                                       \
        const int cb_ = (cb);                                                  \
        if (cb_ == rowbase || cb_ == (rowbase ^ B_HALF)) {                     \
            _Pragma("unroll")                                                  \
            for (int q = 0; q < 16; ++q) {                                     \
                int iq = cb_ + (q & 3) + 8 * (q >> 2) + 4 * hb;                \
                if (iq == j) acc[q] = -INFINITY;                               \
                else if (iq == (j ^ B_HALF)) pos = acc[q];                     \
            }                                                                  \
        }                                                                      \
        float x0 = fmaxf(fmaxf(acc[0], acc[1]), acc[2]);                       \
        float x1 = fmaxf(fmaxf(acc[3], acc[4]), acc[5]);                       \
        float x2 = fmaxf(fmaxf(acc[6], acc[7]), acc[8]);                       \
        float x3 = fmaxf(fmaxf(acc[9], acc[10]), acc[11]);                     \
        float x4 = fmaxf(fmaxf(acc[12], acc[13]), acc[14]);                    \
        float y0 = fmaxf(fmaxf(x0, x1), x2);                                   \
        float y1 = fmaxf(fmaxf(x3, x4), acc[15]);                              \
        float mn = fmaxf(fmaxf(y0, y1), m);                                    \
        float r = __builtin_amdgcn_exp2f(m - mn); /* exp2(0)=1 no-op */        \
        float e0 = __builtin_amdgcn_exp2f(acc[0] - mn);                        \
        float e1 = __builtin_amdgcn_exp2f(acc[1] - mn);                        \
        float e2 = __builtin_amdgcn_exp2f(acc[2] - mn);                        \
        float e3 = __builtin_amdgcn_exp2f(acc[3] - mn);                        \
        float e4 = __builtin_amdgcn_exp2f(acc[4] - mn);                        \
        float e5 = __builtin_amdgcn_exp2f(acc[5] - mn);                        \
        float e6 = __builtin_amdgcn_exp2f(acc[6] - mn);                        \
        float e7 = __builtin_amdgcn_exp2f(acc[7] - mn);                        \
        float e8 = __builtin_amdgcn_exp2f(acc[8] - mn);                        \
        float e9 = __builtin_amdgcn_exp2f(acc[9] - mn);                        \
        float ea = __builtin_amdgcn_exp2f(acc[10] - mn);                       \
        float eb = __builtin_amdgcn_exp2f(acc[11] - mn);                       \
        float ec = __builtin_amdgcn_exp2f(acc[12] - mn);                       \
        float ed = __builtin_amdgcn_exp2f(acc[13] - mn);                       \
        float ee = __builtin_amdgcn_exp2f(acc[14] - mn);                       \
        float ef = __builtin_amdgcn_exp2f(acc[15] - mn);                       \
        float t0 = (e0 + e1) + (e2 + e3);                                      \
        float t1 = (e4 + e5) + (e6 + e7);                                      \
        float t2 = (e8 + e9) + (ea + eb);                                      \
        float t3 = (ec + ed) + (ee + ef);                                      \
        s = s * r + ((t0 + t1) + (t2 + t3));                                   \
        m = mn;                                                                \
    } while (0)

#define ZERO_ACC()                                                             \
    do { _Pragma("unroll") for (int q = 0; q < 16; ++q) acc[q] = 0.f; } while (0)

// ---- kernel 2: main fused GEMM + online LSE (no LDS, no barriers) ----
// 4096 waves: 256 row-waves (32 rows) x 16 col-splits (512 cols).
// 1024 blocks x 256 threads; a block's 4 waves share one col-split.
__global__ __launch_bounds__(256, 2) void ntxent_main(
        const unsigned short* __restrict__ z,
        float* __restrict__ Wm, float* __restrict__ Ws, float* __restrict__ Wp) {
    const int tid = threadIdx.x;
    const int wid = blockIdx.x * 4 + (tid >> 6);
    const int sp = wid >> 8;        // col-split 0..15 (256 row-waves each)
    const int rw = wid & 255;       // row-wave 0..255
    const int l = tid & 63;
    const int l5 = l & 31;
    const int hb = l >> 5;          // k-half select

    const int rowbase = rw * 32;
    const int cb0 = sp * COLS_PER_SPLIT;
    const int j = rowbase + l5;     // this lane's owned row

    // B fragments: 32 owned rows, K=128 in 8 k-steps (named regs)
    const unsigned short* bp = z + (size_t)j * DIM + hb * 8;
    bf16x8 b0 = *(const bf16x8*)(bp + 0 * 16);
    bf16x8 b1 = *(const bf16x8*)(bp + 1 * 16);
    bf16x8 b2 = *(const bf16x8*)(bp + 2 * 16);
    bf16x8 b3 = *(const bf16x8*)(bp + 3 * 16);
    bf16x8 b4 = *(const bf16x8*)(bp + 4 * 16);
    bf16x8 b5 = *(const bf16x8*)(bp + 5 * 16);
    bf16x8 b6 = *(const bf16x8*)(bp + 6 * 16);
    bf16x8 b7 = *(const bf16x8*)(bp + 7 * 16);

    const unsigned short* ap = z + (size_t)(cb0 + l5) * DIM + hb * 8;

    float m = -INFINITY, s = 0.f, pos = -INFINITY;
    bf16x8 aA0, aA1, aA2, aA3, aA4, aA5, aA6, aA7;
    bf16x8 aB0, aB1, aB2, aB3, aB4, aB5, aB6, aB7;
    f32x16 acc;

    LOAD_A(aA, ap);                          // prologue: tile 0

    for (int tp = 0; tp < NTILE / 2; ++tp) { // pair loop, named ping-pong
        const unsigned short* pn1 = ap + (size_t)(2 * tp + 1) * 32 * DIM;
        LOAD_A(aB, pn1);                     // prefetch odd tile
        ZERO_ACC();
        MFMA8(aA);                           // compute even tile
        CONSUME(cb0 + (2 * tp) * 32);

        if (tp + 1 < NTILE / 2) {
            const unsigned short* pn2 = ap + (size_t)(2 * tp + 2) * 32 * DIM;
            LOAD_A(aA, pn2);                 // prefetch next even tile
        }
        ZERO_ACC();
        MFMA8(aB);                           // compute odd tile
        CONSUME(cb0 + (2 * tp + 1) * 32);
    }

    // lanes l and l^32 hold the same row over disjoint stream cols: merge
    {
        float m2 = __shfl_xor(m, 32);
        float s2 = __shfl_xor(s, 32);
        float p2 = __shfl_xor(pos, 32);
        float M = fmaxf(m, m2);
        s = s * __builtin_amdgcn_exp2f(m - M) + s2 * __builtin_amdgcn_exp2f(m2 - M);
        pos = fmaxf(pos, p2);
        if (l < 32) {
            Wm[sp * N_TOT + j] = M;
            Ws[sp * N_TOT + j] = s;
            Wp[sp * N_TOT + j] = pos;
        }
    }
}

// ---- kernel 3: merge splits, compute loss, reduce ----
__global__ void merge_kernel(const float* __restrict__ Wm,
                             const float* __restrict__ Ws,
                             const float* __restrict__ Wp,
                             float* __restrict__ out) {
    int r = blockIdx.x * 256 + threadIdx.x; // 0..8191
    float m = -INFINITY, s = 0.f, p = -INFINITY;
#pragma unroll
    for (int sb = 0; sb < SPLITS; ++sb) {
        float m2 = Wm[sb * N_TOT + r];
        float s2 = Ws[sb * N_TOT + r];
        float p2 = Wp[sb * N_TOT + r];
        float M = fmaxf(m, m2);
        s = s * __builtin_amdgcn_exp2f(m - M) + s2 * __builtin_amdgcn_exp2f(m2 - M);
        m = M;
        p = fmaxf(p, p2);
    }
    // aug row = [pos, neg-row]: add exp(pos) once more
    s += __builtin_amdgcn_exp2f(p - m);
    float loss = ((m + __builtin_amdgcn_logf(s)) - p) * LN2F;

#pragma unroll
    for (int off = 32; off >= 1; off >>= 1)
        loss += __shfl_down(loss, off);
    __shared__ float wsum[4];
    if ((threadIdx.x & 63) == 0) wsum[threadIdx.x >> 6] = loss;
    __syncthreads();
    if (threadIdx.x == 0) {
        float t = wsum[0] + wsum[1] + wsum[2] + wsum[3];
        atomicAdd(out, t * (1.0f / (float)N_TOT));
    }
}

extern "C" void kernel_launch(void* const* d_in, const int* in_sizes, int n_in,
                              void* d_out, int out_size, void* d_ws, size_t ws_size,
                              hipStream_t stream) {
    const float* zi = (const float*)d_in[0];
    const float* zj = (const float*)d_in[1];
    float* out = (float*)d_out;

    unsigned short* z = (unsigned short*)d_ws;                 // 2 MB
    float* Wm = (float*)((char*)d_ws + N_TOT * DIM * 2);
    float* Ws = Wm + SPLITS * N_TOT;
    float* Wp = Ws + SPLITS * N_TOT;

    hipMemsetAsync(d_out, 0, sizeof(float), stream);
    convert_kernel<<<(N_TOT * DIM / 4) / 256, 256, 0, stream>>>(zi, zj, z);
    ntxent_main<<<(256 * SPLITS) / 4, 256, 0, stream>>>(z, Wm, Ws, Wp);
    merge_kernel<<<N_TOT / 256, 256, 0, stream>>>(Wm, Ws, Wp, out);
}

// Round 6
// 46.064 us; speedup vs baseline: 2.9583x; 1.7082x over previous
//
#include <hip/hip_runtime.h>
#include <hip/hip_bf16.h>

// NT-Xent loss, fused flash-LSE over sim = z z^T / T, bf16 32x32x16 MFMA.
// z is pre-packed into FRAGMENT-MAJOR layout zf by the convert kernel:
//   zf[((tile*8 + ks)*64 + l) * 8 .. +8] =
//       bf16(z[tile*32 + (l&31)][(l>>5)*8 + ks*16 .. +8] * PRESCALE)
// so a wave's MFMA operand load is lane-linear: 64 lanes x 16B = one
// contiguous 1KB transaction (vs 64 scattered lines with row-major z --
// round-5 counters showed that made the kernel VMEM-request-rate bound).
// sim is symmetric: A (stream cols) and B (owned rows) use the SAME layout.
// No LDS, no barriers; z = 2MB, L2-resident. Named-register ping-pong
// (no runtime-indexed reg arrays -> no scratch). Branchless deferred-max LSE.

#define N_TOT 8192
#define B_HALF 4096
#define DIM 128
#define SPLITS 32
#define COLS_PER_SPLIT 256
#define NTILE 8                            // 256 / 32
#define PRESCALE 4.5398159686f             // sqrt(log2(e)/0.07)
#define LN2F 0.6931471805599453f

typedef __attribute__((ext_vector_type(8))) short bf16x8;
typedef __attribute__((ext_vector_type(16))) float f32x16;

__device__ __forceinline__ unsigned short f2bf_rne(float f) {
    unsigned int u = __float_as_uint(f);
    u += 0x7FFFu + ((u >> 16) & 1u);
    return (unsigned short)(u >> 16);
}

// ---- kernel 1: convert f32 z_i,z_j -> pre-scaled bf16 fragment-major zf ----
// one thread per 16B fragment-slot; writes coalesced (lane-linear dest).
__global__ void convert_kernel(const float* __restrict__ zi,
                               const float* __restrict__ zj,
                               unsigned short* __restrict__ zf) {
    int t = blockIdx.x * 256 + threadIdx.x;   // slot 0..131071
    int l = t & 63;                           // lane slot
    int ks = (t >> 6) & 7;                    // k-step
    int tile = t >> 9;                        // 32-row tile
    int r = tile * 32 + (l & 31);
    int c = (l >> 5) * 8 + ks * 16;
    long si = (long)r * DIM + c;
    const float* src = (si < (long)B_HALF * DIM) ? (zi + si) : (zj + (si - (long)B_HALF * DIM));
    float4 v0 = *(const float4*)src;
    float4 v1 = *(const float4*)(src + 4);
    bf16x8 o;
    o[0] = (short)f2bf_rne(v0.x * PRESCALE);
    o[1] = (short)f2bf_rne(v0.y * PRESCALE);
    o[2] = (short)f2bf_rne(v0.z * PRESCALE);
    o[3] = (short)f2bf_rne(v0.w * PRESCALE);
    o[4] = (short)f2bf_rne(v1.x * PRESCALE);
    o[5] = (short)f2bf_rne(v1.y * PRESCALE);
    o[6] = (short)f2bf_rne(v1.z * PRESCALE);
    o[7] = (short)f2bf_rne(v1.w * PRESCALE);
    *(bf16x8*)(zf + (size_t)t * 8) = o;
}

// load one 32-col A-tile (8 k-step fragments, 1KB coalesced each)
#define LOAD_A(buf, p)                                                         \
    do {                                                                       \
        buf##0 = *(const bf16x8*)((p) + 0 * 512);                              \
        buf##1 = *(const bf16x8*)((p) + 1 * 512);                              \
        buf##2 = *(const bf16x8*)((p) + 2 * 512);                              \
        buf##3 = *(const bf16x8*)((p) + 3 * 512);                              \
        buf##4 = *(const bf16x8*)((p) + 4 * 512);                              \
        buf##5 = *(const bf16x8*)((p) + 5 * 512);                              \
        buf##6 = *(const bf16x8*)((p) + 6 * 512);                              \
        buf##7 = *(const bf16x8*)((p) + 7 * 512);                              \
    } while (0)

#define MFMA8(buf)                                                             \
    do {                                                                       \
        acc = __builtin_amdgcn_mfma_f32_32x32x16_bf16(buf##0, b0, acc, 0, 0, 0); \
        acc = __builtin_amdgcn_mfma_f32_32x32x16_bf16(buf##1, b1, acc, 0, 0, 0); \
        acc = __builtin_amdgcn_mfma_f32_32x32x16_bf16(buf##2, b2, acc, 0, 0, 0); \
        acc = __builtin_amdgcn_mfma_f32_32x32x16_bf16(buf##3, b3, acc, 0, 0, 0); \
        acc = __builtin_amdgcn_mfma_f32_32x32x16_bf16(buf##4, b4, acc, 0, 0, 0); \
        acc = __builtin_amdgcn_mfma_f32_32x32x16_bf16(buf##5, b5, acc, 0, 0, 0); \
        acc = __builtin_amdgcn_mfma_f32_32x32x16_bf16(buf##6, b6, acc, 0, 0, 0); \
        acc = __builtin_amdgcn_mfma_f32_32x32x16_bf16(buf##7, b7, acc, 0, 0, 0); \
    } while (0)

// consume one 32x32 result tile at stream-col base `cb` into (m,s,pos)
#define CONSUME(cb)                                                            \
    do {                                                                       \
        const int cb_ = (cb);                                                  \
        if (cb_ == rowbase || cb_ == (rowbase ^ B_HALF)) {                     \
            _Pragma("unroll")                                                  \
            for (int q = 0; q < 16; ++q) {                                     \
                int iq = cb_ + (q & 3) + 8 * (q >> 2) + 4 * hb;                \
                if (iq == j) acc[q] = -INFINITY;                               \
                else if (iq == (j ^ B_HALF)) pos = acc[q];                     \
            }                                                                  \
        }                                                                      \
        float x0 = fmaxf(fmaxf(acc[0], acc[1]), acc[2]);                       \
        float x1 = fmaxf(fmaxf(acc[3], acc[4]), acc[5]);                       \
        float x2 = fmaxf(fmaxf(acc[6], acc[7]), acc[8]);                       \
        float x3 = fmaxf(fmaxf(acc[9], acc[10]), acc[11]);                     \
        float x4 = fmaxf(fmaxf(acc[12], acc[13]), acc[14]);                    \
        float y0 = fmaxf(fmaxf(x0, x1), x2);                                   \
        float y1 = fmaxf(fmaxf(x3, x4), acc[15]);                              \
        float mn = fmaxf(fmaxf(y0, y1), m);                                    \
        float r = __builtin_amdgcn_exp2f(m - mn); /* exp2(0)=1 no-op */        \
        float e0 = __builtin_amdgcn_exp2f(acc[0] - mn);                        \
        float e1 = __builtin_amdgcn_exp2f(acc[1] - mn);                        \
        float e2 = __builtin_amdgcn_exp2f(acc[2] - mn);                        \
        float e3 = __builtin_amdgcn_exp2f(acc[3] - mn);                        \
        float e4 = __builtin_amdgcn_exp2f(acc[4] - mn);                        \
        float e5 = __builtin_amdgcn_exp2f(acc[5] - mn);                        \
        float e6 = __builtin_amdgcn_exp2f(acc[6] - mn);                        \
        float e7 = __builtin_amdgcn_exp2f(acc[7] - mn);                        \
        float e8 = __builtin_amdgcn_exp2f(acc[8] - mn);                        \
        float e9 = __builtin_amdgcn_exp2f(acc[9] - mn);                        \
        float ea = __builtin_amdgcn_exp2f(acc[10] - mn);                       \
        float eb = __builtin_amdgcn_exp2f(acc[11] - mn);                       \
        float ec = __builtin_amdgcn_exp2f(acc[12] - mn);                       \
        float ed = __builtin_amdgcn_exp2f(acc[13] - mn);                       \
        float ee = __builtin_amdgcn_exp2f(acc[14] - mn);                       \
        float ef = __builtin_amdgcn_exp2f(acc[15] - mn);                       \
        float t0 = (e0 + e1) + (e2 + e3);                                      \
        float t1 = (e4 + e5) + (e6 + e7);                                      \
        float t2 = (e8 + e9) + (ea + eb);                                      \
        float t3 = (ec + ed) + (ee + ef);                                      \
        s = s * r + ((t0 + t1) + (t2 + t3));                                   \
        m = mn;                                                                \
    } while (0)

#define ZERO_ACC()                                                             \
    do { _Pragma("unroll") for (int q = 0; q < 16; ++q) acc[q] = 0.f; } while (0)

// ---- kernel 2: main fused GEMM + online LSE (no LDS, no barriers) ----
// 8192 waves: 256 row-waves (32 rows) x 32 col-splits (256 cols).
// 2048 blocks x 256 threads; a block's 4 waves share one col-split (L1 reuse).
__global__ __launch_bounds__(256, 2) void ntxent_main(
        const unsigned short* __restrict__ zf,
        float* __restrict__ Wm, float* __restrict__ Ws, float* __restrict__ Wp) {
    const int tid = threadIdx.x;
    const int wid = blockIdx.x * 4 + (tid >> 6);
    const int sp = wid >> 8;        // col-split 0..31
    const int rw = wid & 255;       // row-wave 0..255 (= row tile)
    const int l = tid & 63;
    const int l5 = l & 31;
    const int hb = l >> 5;          // k-half select

    const int rowbase = rw * 32;
    const int cb0 = sp * COLS_PER_SPLIT;
    const int j = rowbase + l5;     // this lane's owned row

    // B fragments: coalesced 1KB loads from fragment-major zf
    const unsigned short* bp = zf + (size_t)rw * 4096 + l * 8;
    bf16x8 b0 = *(const bf16x8*)(bp + 0 * 512);
    bf16x8 b1 = *(const bf16x8*)(bp + 1 * 512);
    bf16x8 b2 = *(const bf16x8*)(bp + 2 * 512);
    bf16x8 b3 = *(const bf16x8*)(bp + 3 * 512);
    bf16x8 b4 = *(const bf16x8*)(bp + 4 * 512);
    bf16x8 b5 = *(const bf16x8*)(bp + 5 * 512);
    bf16x8 b6 = *(const bf16x8*)(bp + 6 * 512);
    bf16x8 b7 = *(const bf16x8*)(bp + 7 * 512);

    const unsigned short* ap = zf + (size_t)(cb0 >> 5) * 4096 + l * 8;

    float m = -INFINITY, s = 0.f, pos = -INFINITY;
    bf16x8 aA0, aA1, aA2, aA3, aA4, aA5, aA6, aA7;
    bf16x8 aB0, aB1, aB2, aB3, aB4, aB5, aB6, aB7;
    f32x16 acc;

    LOAD_A(aA, ap);                          // prologue: tile 0

    for (int tp = 0; tp < NTILE / 2; ++tp) { // pair loop, named ping-pong
        const unsigned short* pn1 = ap + (size_t)(2 * tp + 1) * 4096;
        LOAD_A(aB, pn1);                     // prefetch odd tile
        ZERO_ACC();
        MFMA8(aA);                           // compute even tile
        CONSUME(cb0 + (2 * tp) * 32);

        if (tp + 1 < NTILE / 2) {
            const unsigned short* pn2 = ap + (size_t)(2 * tp + 2) * 4096;
            LOAD_A(aA, pn2);                 // prefetch next even tile
        }
        ZERO_ACC();
        MFMA8(aB);                           // compute odd tile
        CONSUME(cb0 + (2 * tp + 1) * 32);
    }

    // lanes l and l^32 hold the same row over disjoint stream cols: merge
    {
        float m2 = __shfl_xor(m, 32);
        float s2 = __shfl_xor(s, 32);
        float p2 = __shfl_xor(pos, 32);
        float M = fmaxf(m, m2);
        s = s * __builtin_amdgcn_exp2f(m - M) + s2 * __builtin_amdgcn_exp2f(m2 - M);
        pos = fmaxf(pos, p2);
        if (l < 32) {
            Wm[sp * N_TOT + j] = M;
            Ws[sp * N_TOT + j] = s;
            Wp[sp * N_TOT + j] = pos;
        }
    }
}

// ---- kernel 3: merge splits, compute loss, reduce ----
__global__ void merge_kernel(const float* __restrict__ Wm,
                             const float* __restrict__ Ws,
                             const float* __restrict__ Wp,
                             float* __restrict__ out) {
    int r = blockIdx.x * 256 + threadIdx.x; // 0..8191
    float m = -INFINITY, s = 0.f, p = -INFINITY;
#pragma unroll
    for (int sb = 0; sb < SPLITS; ++sb) {
        float m2 = Wm[sb * N_TOT + r];
        float s2 = Ws[sb * N_TOT + r];
        float p2 = Wp[sb * N_TOT + r];
        float M = fmaxf(m, m2);
        s = s * __builtin_amdgcn_exp2f(m - M) + s2 * __builtin_amdgcn_exp2f(m2 - M);
        m = M;
        p = fmaxf(p, p2);
    }
    // aug row = [pos, neg-row]: add exp(pos) once more
    s += __builtin_amdgcn_exp2f(p - m);
    float loss = ((m + __builtin_amdgcn_logf(s)) - p) * LN2F;

#pragma unroll
    for (int off = 32; off >= 1; off >>= 1)
        loss += __shfl_down(loss, off);
    __shared__ float wsum[4];
    if ((threadIdx.x & 63) == 0) wsum[threadIdx.x >> 6] = loss;
    __syncthreads();
    if (threadIdx.x == 0) {
        float t = wsum[0] + wsum[1] + wsum[2] + wsum[3];
        atomicAdd(out, t * (1.0f / (float)N_TOT));
    }
}

extern "C" void kernel_launch(void* const* d_in, const int* in_sizes, int n_in,
                              void* d_out, int out_size, void* d_ws, size_t ws_size,
                              hipStream_t stream) {
    const float* zi = (const float*)d_in[0];
    const float* zj = (const float*)d_in[1];
    float* out = (float*)d_out;

    unsigned short* zf = (unsigned short*)d_ws;                // 2 MB
    float* Wm = (float*)((char*)d_ws + (size_t)N_TOT * DIM * 2);
    float* Ws = Wm + SPLITS * N_TOT;
    float* Wp = Ws + SPLITS * N_TOT;

    hipMemsetAsync(d_out, 0, sizeof(float), stream);
    convert_kernel<<<(N_TOT * DIM / 8) / 256, 256, 0, stream>>>(zi, zj, zf);
    ntxent_main<<<(256 * SPLITS) / 4, 256, 0, stream>>>(zf, Wm, Ws, Wp);
    merge_kernel<<<N_TOT / 256, 256, 0, stream>>>(Wm, Ws, Wp, out);
}

// Round 7
// 44.797 us; speedup vs baseline: 3.0420x; 1.0283x over previous
//
#include <hip/hip_runtime.h>
#include <hip/hip_bf16.h>

// NT-Xent loss, fused flash-LSE over sim = z z^T / T, bf16 32x32x16 MFMA.
// z is pre-packed into FRAGMENT-MAJOR layout zf (convert kernel):
//   zf[((tile*8 + ks)*64 + l) * 8 .. +8] =
//       bf16(z[tile*32 + (l&31)][(l>>5)*8 + ks*16 .. +8] * PRESCALE)
// -> every MFMA operand load is one contiguous 1KB wave transaction.
// sim is symmetric: A (stream cols) and B (owned rows) share the layout.
// No LDS, no barriers; zf = 2MB, L2-resident.
// ROUND 7: __builtin_amdgcn_sched_barrier(0) fences pin the load clusters
// ahead of the compute phases -- R5/R6's compiler schedule collapsed the
// named ping-pong (VGPR_Count=64 proved loads were sunk to point-of-use,
// leaving ~1 outstanding VMEM/wave -> latency-bound at ~35us).

#define N_TOT 8192
#define B_HALF 4096
#define DIM 128
#define SPLITS 32
#define COLS_PER_SPLIT 256
#define NTILE 8                            // 256 / 32
#define PRESCALE 4.5398159686f             // sqrt(log2(e)/0.07)
#define LN2F 0.6931471805599453f

typedef __attribute__((ext_vector_type(8))) short bf16x8;
typedef __attribute__((ext_vector_type(16))) float f32x16;

#define SCHED_FENCE() __builtin_amdgcn_sched_barrier(0)

__device__ __forceinline__ unsigned short f2bf_rne(float f) {
    unsigned int u = __float_as_uint(f);
    u += 0x7FFFu + ((u >> 16) & 1u);
    return (unsigned short)(u >> 16);
}

// ---- kernel 1: convert f32 z_i,z_j -> pre-scaled bf16 fragment-major zf ----
__global__ void convert_kernel(const float* __restrict__ zi,
                               const float* __restrict__ zj,
                               unsigned short* __restrict__ zf) {
    int t = blockIdx.x * 256 + threadIdx.x;   // slot 0..131071
    int l = t & 63;                           // lane slot
    int ks = (t >> 6) & 7;                    // k-step
    int tile = t >> 9;                        // 32-row tile
    int r = tile * 32 + (l & 31);
    int c = (l >> 5) * 8 + ks * 16;
    long si = (long)r * DIM + c;
    const float* src = (si < (long)B_HALF * DIM) ? (zi + si) : (zj + (si - (long)B_HALF * DIM));
    float4 v0 = *(const float4*)src;
    float4 v1 = *(const float4*)(src + 4);
    bf16x8 o;
    o[0] = (short)f2bf_rne(v0.x * PRESCALE);
    o[1] = (short)f2bf_rne(v0.y * PRESCALE);
    o[2] = (short)f2bf_rne(v0.z * PRESCALE);
    o[3] = (short)f2bf_rne(v0.w * PRESCALE);
    o[4] = (short)f2bf_rne(v1.x * PRESCALE);
    o[5] = (short)f2bf_rne(v1.y * PRESCALE);
    o[6] = (short)f2bf_rne(v1.z * PRESCALE);
    o[7] = (short)f2bf_rne(v1.w * PRESCALE);
    *(bf16x8*)(zf + (size_t)t * 8) = o;
}

// load one 32-col A-tile (8 k-step fragments, 1KB coalesced each)
#define LOAD_A(buf, p)                                                         \
    do {                                                                       \
        buf##0 = *(const bf16x8*)((p) + 0 * 512);                              \
        buf##1 = *(const bf16x8*)((p) + 1 * 512);                              \
        buf##2 = *(const bf16x8*)((p) + 2 * 512);                              \
        buf##3 = *(const bf16x8*)((p) + 3 * 512);                              \
        buf##4 = *(const bf16x8*)((p) + 4 * 512);                              \
        buf##5 = *(const bf16x8*)((p) + 5 * 512);                              \
        buf##6 = *(const bf16x8*)((p) + 6 * 512);                              \
        buf##7 = *(const bf16x8*)((p) + 7 * 512);                              \
    } while (0)

#define MFMA8(buf)                                                             \
    do {                                                                       \
        acc = __builtin_amdgcn_mfma_f32_32x32x16_bf16(buf##0, b0, acc, 0, 0, 0); \
        acc = __builtin_amdgcn_mfma_f32_32x32x16_bf16(buf##1, b1, acc, 0, 0, 0); \
        acc = __builtin_amdgcn_mfma_f32_32x32x16_bf16(buf##2, b2, acc, 0, 0, 0); \
        acc = __builtin_amdgcn_mfma_f32_32x32x16_bf16(buf##3, b3, acc, 0, 0, 0); \
        acc = __builtin_amdgcn_mfma_f32_32x32x16_bf16(buf##4, b4, acc, 0, 0, 0); \
        acc = __builtin_amdgcn_mfma_f32_32x32x16_bf16(buf##5, b5, acc, 0, 0, 0); \
        acc = __builtin_amdgcn_mfma_f32_32x32x16_bf16(buf##6, b6, acc, 0, 0, 0); \
        acc = __builtin_amdgcn_mfma_f32_32x32x16_bf16(buf##7, b7, acc, 0, 0, 0); \
    } while (0)

// consume one 32x32 result tile at stream-col base `cb` into (m,s,pos)
#define CONSUME(cb)                                                            \
    do {                                                                       \
        const int cb_ = (cb);                                                  \
        if (cb_ == rowbase || cb_ == (rowbase ^ B_HALF)) {                     \
            _Pragma("unroll")                                                  \
            for (int q = 0; q < 16; ++q) {                                     \
                int iq = cb_ + (q & 3) + 8 * (q >> 2) + 4 * hb;                \
                if (iq == j) acc[q] = -INFINITY;                               \
                else if (iq == (j ^ B_HALF)) pos = acc[q];                     \
            }                                                                  \
        }                                                                      \
        float x0 = fmaxf(fmaxf(acc[0], acc[1]), acc[2]);                       \
        float x1 = fmaxf(fmaxf(acc[3], acc[4]), acc[5]);                       \
        float x2 = fmaxf(fmaxf(acc[6], acc[7]), acc[8]);                       \
        float x3 = fmaxf(fmaxf(acc[9], acc[10]), acc[11]);                     \
        float x4 = fmaxf(fmaxf(acc[12], acc[13]), acc[14]);                    \
        float y0 = fmaxf(fmaxf(x0, x1), x2);                                   \
        float y1 = fmaxf(fmaxf(x3, x4), acc[15]);                              \
        float mn = fmaxf(fmaxf(y0, y1), m);                                    \
        float r = __builtin_amdgcn_exp2f(m - mn); /* exp2(0)=1 no-op */        \
        float e0 = __builtin_amdgcn_exp2f(acc[0] - mn);                        \
        float e1 = __builtin_amdgcn_exp2f(acc[1] - mn);                        \
        float e2 = __builtin_amdgcn_exp2f(acc[2] - mn);                        \
        float e3 = __builtin_amdgcn_exp2f(acc[3] - mn);                        \
        float e4 = __builtin_amdgcn_exp2f(acc[4] - mn);                        \
        float e5 = __builtin_amdgcn_exp2f(acc[5] - mn);                        \
        float e6 = __builtin_amdgcn_exp2f(acc[6] - mn);                        \
        float e7 = __builtin_amdgcn_exp2f(acc[7] - mn);                        \
        float e8 = __builtin_amdgcn_exp2f(acc[8] - mn);                        \
        float e9 = __builtin_amdgcn_exp2f(acc[9] - mn);                        \
        float ea = __builtin_amdgcn_exp2f(acc[10] - mn);                       \
        float eb = __builtin_amdgcn_exp2f(acc[11] - mn);                       \
        float ec = __builtin_amdgcn_exp2f(acc[12] - mn);                       \
        float ed = __builtin_amdgcn_exp2f(acc[13] - mn);                       \
        float ee = __builtin_amdgcn_exp2f(acc[14] - mn);                       \
        float ef = __builtin_amdgcn_exp2f(acc[15] - mn);                       \
        float t0 = (e0 + e1) + (e2 + e3);                                      \
        float t1 = (e4 + e5) + (e6 + e7);                                      \
        float t2 = (e8 + e9) + (ea + eb);                                      \
        float t3 = (ec + ed) + (ee + ef);                                      \
        s = s * r + ((t0 + t1) + (t2 + t3));                                   \
        m = mn;                                                                \
    } while (0)

#define ZERO_ACC()                                                             \
    do { _Pragma("unroll") for (int q = 0; q < 16; ++q) acc[q] = 0.f; } while (0)

// ---- kernel 2: main fused GEMM + online LSE (no LDS, no barriers) ----
// 8192 waves: 256 row-waves (32 rows) x 32 col-splits (256 cols).
// 2048 blocks x 256 threads; a block's 4 waves share one col-split (L1 reuse).
__global__ __launch_bounds__(256, 2) void ntxent_main(
        const unsigned short* __restrict__ zf,
        float* __restrict__ Wm, float* __restrict__ Ws, float* __restrict__ Wp) {
    const int tid = threadIdx.x;
    const int wid = blockIdx.x * 4 + (tid >> 6);
    const int sp = wid >> 8;        // col-split 0..31
    const int rw = wid & 255;       // row-wave 0..255 (= row tile)
    const int l = tid & 63;
    const int l5 = l & 31;
    const int hb = l >> 5;          // k-half select

    const int rowbase = rw * 32;
    const int cb0 = sp * COLS_PER_SPLIT;
    const int j = rowbase + l5;     // this lane's owned row

    // B fragments: coalesced 1KB loads from fragment-major zf
    const unsigned short* bp = zf + (size_t)rw * 4096 + l * 8;
    bf16x8 b0 = *(const bf16x8*)(bp + 0 * 512);
    bf16x8 b1 = *(const bf16x8*)(bp + 1 * 512);
    bf16x8 b2 = *(const bf16x8*)(bp + 2 * 512);
    bf16x8 b3 = *(const bf16x8*)(bp + 3 * 512);
    bf16x8 b4 = *(const bf16x8*)(bp + 4 * 512);
    bf16x8 b5 = *(const bf16x8*)(bp + 5 * 512);
    bf16x8 b6 = *(const bf16x8*)(bp + 6 * 512);
    bf16x8 b7 = *(const bf16x8*)(bp + 7 * 512);

    const unsigned short* ap = zf + (size_t)(cb0 >> 5) * 4096 + l * 8;

    float m = -INFINITY, s = 0.f, pos = -INFINITY;
    bf16x8 aA0, aA1, aA2, aA3, aA4, aA5, aA6, aA7;
    bf16x8 aB0, aB1, aB2, aB3, aB4, aB5, aB6, aB7;
    f32x16 acc;

    LOAD_A(aA, ap);                          // prologue: tile 0
    SCHED_FENCE();

    for (int tp = 0; tp < NTILE / 2; ++tp) { // pair loop, named ping-pong
        const unsigned short* pn1 = ap + (size_t)(2 * tp + 1) * 4096;
        LOAD_A(aB, pn1);                     // prefetch odd tile (8 in flight)
        SCHED_FENCE();                       // pin loads before compute
        ZERO_ACC();
        MFMA8(aA);                           // compute even tile
        CONSUME(cb0 + (2 * tp) * 32);
        SCHED_FENCE();                       // end even-compute region

        if (tp + 1 < NTILE / 2) {
            const unsigned short* pn2 = ap + (size_t)(2 * tp + 2) * 4096;
            LOAD_A(aA, pn2);                 // prefetch next even tile
        }
        SCHED_FENCE();                       // pin loads before compute
        ZERO_ACC();
        MFMA8(aB);                           // compute odd tile
        CONSUME(cb0 + (2 * tp + 1) * 32);
        SCHED_FENCE();                       // end odd-compute region
    }

    // lanes l and l^32 hold the same row over disjoint stream cols: merge
    {
        float m2 = __shfl_xor(m, 32);
        float s2 = __shfl_xor(s, 32);
        float p2 = __shfl_xor(pos, 32);
        float M = fmaxf(m, m2);
        s = s * __builtin_amdgcn_exp2f(m - M) + s2 * __builtin_amdgcn_exp2f(m2 - M);
        pos = fmaxf(pos, p2);
        if (l < 32) {
            Wm[sp * N_TOT + j] = M;
            Ws[sp * N_TOT + j] = s;
            Wp[sp * N_TOT + j] = pos;
        }
    }
}

// ---- kernel 3: merge splits, compute loss, reduce ----
__global__ void merge_kernel(const float* __restrict__ Wm,
                             const float* __restrict__ Ws,
                             const float* __restrict__ Wp,
                             float* __restrict__ out) {
    int r = blockIdx.x * 256 + threadIdx.x; // 0..8191
    float m = -INFINITY, s = 0.f, p = -INFINITY;
#pragma unroll
    for (int sb = 0; sb < SPLITS; ++sb) {
        float m2 = Wm[sb * N_TOT + r];
        float s2 = Ws[sb * N_TOT + r];
        float p2 = Wp[sb * N_TOT + r];
        float M = fmaxf(m, m2);
        s = s * __builtin_amdgcn_exp2f(m - M) + s2 * __builtin_amdgcn_exp2f(m2 - M);
        m = M;
        p = fmaxf(p, p2);
    }
    // aug row = [pos, neg-row]: add exp(pos) once more
    s += __builtin_amdgcn_exp2f(p - m);
    float loss = ((m + __builtin_amdgcn_logf(s)) - p) * LN2F;

#pragma unroll
    for (int off = 32; off >= 1; off >>= 1)
        loss += __shfl_down(loss, off);
    __shared__ float wsum[4];
    if ((threadIdx.x & 63) == 0) wsum[threadIdx.x >> 6] = loss;
    __syncthreads();
    if (threadIdx.x == 0) {
        float t = wsum[0] + wsum[1] + wsum[2] + wsum[3];
        atomicAdd(out, t * (1.0f / (float)N_TOT));
    }
}

extern "C" void kernel_launch(void* const* d_in, const int* in_sizes, int n_in,
                              void* d_out, int out_size, void* d_ws, size_t ws_size,
                              hipStream_t stream) {
    const float* zi = (const float*)d_in[0];
    const float* zj = (const float*)d_in[1];
    float* out = (float*)d_out;

    unsigned short* zf = (unsigned short*)d_ws;                // 2 MB
    float* Wm = (float*)((char*)d_ws + (size_t)N_TOT * DIM * 2);
    float* Ws = Wm + SPLITS * N_TOT;
    float* Wp = Ws + SPLITS * N_TOT;

    hipMemsetAsync(d_out, 0, sizeof(float), stream);
    convert_kernel<<<(N_TOT * DIM / 8) / 256, 256, 0, stream>>>(zi, zj, zf);
    ntxent_main<<<(256 * SPLITS) / 4, 256, 0, stream>>>(zf, Wm, Ws, Wp);
    merge_kernel<<<N_TOT / 256, 256, 0, stream>>>(Wm, Ws, Wp, out);
}

// Round 8
// 41.722 us; speedup vs baseline: 3.2662x; 1.0737x over previous
//
#include <hip/hip_runtime.h>
#include <hip/hip_bf16.h>

// NT-Xent loss, fused flash-LSE over sim = z z^T / T, bf16 32x32x16 MFMA.
// z pre-packed into FRAGMENT-MAJOR zf (convert kernel):
//   zf[((tile*8 + ks)*64 + l) * 8 .. +8] =
//       bf16(z[tile*32 + (l&31)][(l>>5)*8 + ks*16 .. +8] * PRESCALE)
// -> every MFMA operand load = one contiguous 1KB wave transaction.
// sim symmetric: A (stream cols) and B (owned rows) share the layout.
// ROUND 8: R5-R7 were L2-BW-bound (537 MB of A-reads at 32 rows/wave =
// ~16 TB/s effective = the wall). Now 64 rows/wave (two named B-sets, two
// accs): A-traffic halves to 268 MB and each A-fragment feeds 2 MFMAs.
// Block's 4 waves share the col-split; raw s_barrier (NO waitcnt drain)
// convoys them so trailing waves hit the 8KB A-tile in L1.
// All register arrays are compile-time indexed (no scratch).

#define N_TOT 8192
#define B_HALF 4096
#define DIM 128
#define SPLITS 32
#define COLS_PER_SPLIT 256
#define NTILE 8                            // 256 / 32
#define PRESCALE 4.5398159686f             // sqrt(log2(e)/0.07)
#define LN2F 0.6931471805599453f

typedef __attribute__((ext_vector_type(8))) short bf16x8;
typedef __attribute__((ext_vector_type(16))) float f32x16;

#define SCHED_FENCE() __builtin_amdgcn_sched_barrier(0)

__device__ __forceinline__ unsigned short f2bf_rne(float f) {
    unsigned int u = __float_as_uint(f);
    u += 0x7FFFu + ((u >> 16) & 1u);
    return (unsigned short)(u >> 16);
}

// ---- kernel 1: convert f32 z_i,z_j -> pre-scaled bf16 fragment-major zf ----
__global__ void convert_kernel(const float* __restrict__ zi,
                               const float* __restrict__ zj,
                               unsigned short* __restrict__ zf) {
    int t = blockIdx.x * 256 + threadIdx.x;   // slot 0..131071
    int l = t & 63;                           // lane slot
    int ks = (t >> 6) & 7;                    // k-step
    int tile = t >> 9;                        // 32-row tile
    int r = tile * 32 + (l & 31);
    int c = (l >> 5) * 8 + ks * 16;
    long si = (long)r * DIM + c;
    const float* src = (si < (long)B_HALF * DIM) ? (zi + si) : (zj + (si - (long)B_HALF * DIM));
    float4 v0 = *(const float4*)src;
    float4 v1 = *(const float4*)(src + 4);
    bf16x8 o;
    o[0] = (short)f2bf_rne(v0.x * PRESCALE);
    o[1] = (short)f2bf_rne(v0.y * PRESCALE);
    o[2] = (short)f2bf_rne(v0.z * PRESCALE);
    o[3] = (short)f2bf_rne(v0.w * PRESCALE);
    o[4] = (short)f2bf_rne(v1.x * PRESCALE);
    o[5] = (short)f2bf_rne(v1.y * PRESCALE);
    o[6] = (short)f2bf_rne(v1.z * PRESCALE);
    o[7] = (short)f2bf_rne(v1.w * PRESCALE);
    *(bf16x8*)(zf + (size_t)t * 8) = o;
}

// load one 32-col A-tile (8 k-step fragments, 1KB coalesced each)
#define LOAD_A(buf, p)                                                         \
    do {                                                                       \
        buf##0 = *(const bf16x8*)((p) + 0 * 512);                              \
        buf##1 = *(const bf16x8*)((p) + 1 * 512);                              \
        buf##2 = *(const bf16x8*)((p) + 2 * 512);                              \
        buf##3 = *(const bf16x8*)((p) + 3 * 512);                              \
        buf##4 = *(const bf16x8*)((p) + 4 * 512);                              \
        buf##5 = *(const bf16x8*)((p) + 5 * 512);                              \
        buf##6 = *(const bf16x8*)((p) + 6 * 512);                              \
        buf##7 = *(const bf16x8*)((p) + 7 * 512);                              \
    } while (0)

#define MFMA8(accv, abuf, bs)                                                  \
    do {                                                                       \
        accv = __builtin_amdgcn_mfma_f32_32x32x16_bf16(abuf##0, bs##0, accv, 0, 0, 0); \
        accv = __builtin_amdgcn_mfma_f32_32x32x16_bf16(abuf##1, bs##1, accv, 0, 0, 0); \
        accv = __builtin_amdgcn_mfma_f32_32x32x16_bf16(abuf##2, bs##2, accv, 0, 0, 0); \
        accv = __builtin_amdgcn_mfma_f32_32x32x16_bf16(abuf##3, bs##3, accv, 0, 0, 0); \
        accv = __builtin_amdgcn_mfma_f32_32x32x16_bf16(abuf##4, bs##4, accv, 0, 0, 0); \
        accv = __builtin_amdgcn_mfma_f32_32x32x16_bf16(abuf##5, bs##5, accv, 0, 0, 0); \
        accv = __builtin_amdgcn_mfma_f32_32x32x16_bf16(abuf##6, bs##6, accv, 0, 0, 0); \
        accv = __builtin_amdgcn_mfma_f32_32x32x16_bf16(abuf##7, bs##7, accv, 0, 0, 0); \
    } while (0)

// consume one 32x32 result tile (acc) for rows [rbase, rbase+32) at
// stream-col base cb into (mv, sv, pv). Branchless deferred-max LSE.
#define CONSUME(accv, mv, sv, pv, rbase, cbv)                                  \
    do {                                                                       \
        const int cb_ = (cbv);                                                 \
        const int rb_ = (rbase);                                               \
        if (cb_ == rb_ || cb_ == (rb_ ^ B_HALF)) {                             \
            const int j_ = rb_ + l5;                                           \
            _Pragma("unroll")                                                  \
            for (int q = 0; q < 16; ++q) {                                     \
                int iq = cb_ + (q & 3) + 8 * (q >> 2) + 4 * hb;                \
                if (iq == j_) accv[q] = -INFINITY;                             \
                else if (iq == (j_ ^ B_HALF)) pv = accv[q];                    \
            }                                                                  \
        }                                                                      \
        float x0 = fmaxf(fmaxf(accv[0], accv[1]), accv[2]);                    \
        float x1 = fmaxf(fmaxf(accv[3], accv[4]), accv[5]);                    \
        float x2 = fmaxf(fmaxf(accv[6], accv[7]), accv[8]);                    \
        float x3 = fmaxf(fmaxf(accv[9], accv[10]), accv[11]);                  \
        float x4 = fmaxf(fmaxf(accv[12], accv[13]), accv[14]);                 \
        float y0 = fmaxf(fmaxf(x0, x1), x2);                                   \
        float y1 = fmaxf(fmaxf(x3, x4), accv[15]);                             \
        float mn = fmaxf(fmaxf(y0, y1), mv);                                   \
        float rr = __builtin_amdgcn_exp2f(mv - mn); /* exp2(0)=1 no-op */      \
        float e0 = __builtin_amdgcn_exp2f(accv[0] - mn);                       \
        float e1 = __builtin_amdgcn_exp2f(accv[1] - mn);                       \
        float e2 = __builtin_amdgcn_exp2f(accv[2] - mn);                       \
        float e3 = __builtin_amdgcn_exp2f(accv[3] - mn);                       \
        float e4 = __builtin_amdgcn_exp2f(accv[4] - mn);                       \
        float e5 = __builtin_amdgcn_exp2f(accv[5] - mn);                       \
        float e6 = __builtin_amdgcn_exp2f(accv[6] - mn);                       \
        float e7 = __builtin_amdgcn_exp2f(accv[7] - mn);                       \
        float e8 = __builtin_amdgcn_exp2f(accv[8] - mn);                       \
        float e9 = __builtin_amdgcn_exp2f(accv[9] - mn);                       \
        float ea = __builtin_amdgcn_exp2f(accv[10] - mn);                      \
        float eb = __builtin_amdgcn_exp2f(accv[11] - mn);                      \
        float ec = __builtin_amdgcn_exp2f(accv[12] - mn);                      \
        float ed = __builtin_amdgcn_exp2f(accv[13] - mn);                      \
        float ee = __builtin_amdgcn_exp2f(accv[14] - mn);                      \
        float ef = __builtin_amdgcn_exp2f(accv[15] - mn);                      \
        float t0 = (e0 + e1) + (e2 + e3);                                      \
        float t1 = (e4 + e5) + (e6 + e7);                                      \
        float t2 = (e8 + e9) + (ea + eb);                                      \
        float t3 = (ec + ed) + (ee + ef);                                      \
        sv = sv * rr + ((t0 + t1) + (t2 + t3));                                \
        mv = mn;                                                               \
    } while (0)

#define ZERO16(accv)                                                           \
    do { _Pragma("unroll") for (int q = 0; q < 16; ++q) accv[q] = 0.f; } while (0)

// ---- kernel 2: main fused GEMM + online LSE (no LDS, reg-resident B) ----
// 4096 waves: 128 row-waves (64 rows) x 32 col-splits (256 cols).
// 1024 blocks x 256 threads; a block's 4 waves convoy one col-split (L1).
__global__ __launch_bounds__(256, 2) void ntxent_main(
        const unsigned short* __restrict__ zf,
        float* __restrict__ Wm, float* __restrict__ Ws, float* __restrict__ Wp) {
    const int tid = threadIdx.x;
    const int wid = blockIdx.x * 4 + (tid >> 6);
    const int sp = wid >> 7;        // col-split 0..31
    const int rw = wid & 127;       // row-wave 0..127 (owns 64 rows)
    const int l = tid & 63;
    const int l5 = l & 31;
    const int hb = l >> 5;          // k-half select

    const int rowbase = rw * 64;
    const int cb0 = sp * COLS_PER_SPLIT;

    // B fragments: two 32-row tile-sets, coalesced 1KB loads from zf
    const unsigned short* bp = zf + (size_t)(rw * 2) * 4096 + l * 8;
    bf16x8 b00 = *(const bf16x8*)(bp + 0 * 512);
    bf16x8 b01 = *(const bf16x8*)(bp + 1 * 512);
    bf16x8 b02 = *(const bf16x8*)(bp + 2 * 512);
    bf16x8 b03 = *(const bf16x8*)(bp + 3 * 512);
    bf16x8 b04 = *(const bf16x8*)(bp + 4 * 512);
    bf16x8 b05 = *(const bf16x8*)(bp + 5 * 512);
    bf16x8 b06 = *(const bf16x8*)(bp + 6 * 512);
    bf16x8 b07 = *(const bf16x8*)(bp + 7 * 512);
    const unsigned short* bq = bp + 4096;
    bf16x8 b10 = *(const bf16x8*)(bq + 0 * 512);
    bf16x8 b11 = *(const bf16x8*)(bq + 1 * 512);
    bf16x8 b12 = *(const bf16x8*)(bq + 2 * 512);
    bf16x8 b13 = *(const bf16x8*)(bq + 3 * 512);
    bf16x8 b14 = *(const bf16x8*)(bq + 4 * 512);
    bf16x8 b15 = *(const bf16x8*)(bq + 5 * 512);
    bf16x8 b16 = *(const bf16x8*)(bq + 6 * 512);
    bf16x8 b17 = *(const bf16x8*)(bq + 7 * 512);

    const unsigned short* ap = zf + (size_t)(cb0 >> 5) * 4096 + l * 8;

    float m0 = -INFINITY, s0 = 0.f, p0 = -INFINITY;
    float m1 = -INFINITY, s1 = 0.f, p1 = -INFINITY;
    bf16x8 aA0, aA1, aA2, aA3, aA4, aA5, aA6, aA7;
    bf16x8 aB0, aB1, aB2, aB3, aB4, aB5, aB6, aB7;
    f32x16 accA, accB;

    LOAD_A(aA, ap);                          // prologue: tile 0
    SCHED_FENCE();

    for (int tp = 0; tp < NTILE / 2; ++tp) { // pair loop, named ping-pong
        const unsigned short* pn1 = ap + (size_t)(2 * tp + 1) * 4096;
        LOAD_A(aB, pn1);                     // prefetch odd tile
        SCHED_FENCE();
        ZERO16(accA); ZERO16(accB);
        MFMA8(accA, aA, b0);                 // even tile x both row-sets
        MFMA8(accB, aA, b1);
        {
            const int cbe = cb0 + (2 * tp) * 32;
            CONSUME(accA, m0, s0, p0, rowbase, cbe);
            CONSUME(accB, m1, s1, p1, rowbase + 32, cbe);
        }
        SCHED_FENCE();

        if (tp + 1 < NTILE / 2) {
            const unsigned short* pn2 = ap + (size_t)(2 * tp + 2) * 4096;
            LOAD_A(aA, pn2);                 // prefetch next even tile
        }
        SCHED_FENCE();
        ZERO16(accA); ZERO16(accB);
        MFMA8(accA, aB, b0);                 // odd tile x both row-sets
        MFMA8(accB, aB, b1);
        {
            const int cbo = cb0 + (2 * tp + 1) * 32;
            CONSUME(accA, m0, s0, p0, rowbase, cbo);
            CONSUME(accB, m1, s1, p1, rowbase + 32, cbo);
        }
        SCHED_FENCE();
        // convoy the block's 4 waves for L1 A-tile reuse.
        // raw s_barrier: no waitcnt drain, prefetch stays in flight.
        __builtin_amdgcn_s_barrier();
    }

    // lanes l and l^32 hold the same row over disjoint stream cols: merge
    {
        float m2 = __shfl_xor(m0, 32);
        float s2 = __shfl_xor(s0, 32);
        float q2 = __shfl_xor(p0, 32);
        float M = fmaxf(m0, m2);
        s0 = s0 * __builtin_amdgcn_exp2f(m0 - M) + s2 * __builtin_amdgcn_exp2f(m2 - M);
        p0 = fmaxf(p0, q2);
        if (l < 32) {
            int r = rowbase + l;
            Wm[sp * N_TOT + r] = M;
            Ws[sp * N_TOT + r] = s0;
            Wp[sp * N_TOT + r] = p0;
        }
    }
    {
        float m2 = __shfl_xor(m1, 32);
        float s2 = __shfl_xor(s1, 32);
        float q2 = __shfl_xor(p1, 32);
        float M = fmaxf(m1, m2);
        s1 = s1 * __builtin_amdgcn_exp2f(m1 - M) + s2 * __builtin_amdgcn_exp2f(m2 - M);
        p1 = fmaxf(p1, q2);
        if (l < 32) {
            int r = rowbase + 32 + l;
            Wm[sp * N_TOT + r] = M;
            Ws[sp * N_TOT + r] = s1;
            Wp[sp * N_TOT + r] = p1;
        }
    }
}

// ---- kernel 3: merge splits, compute loss, reduce ----
__global__ void merge_kernel(const float* __restrict__ Wm,
                             const float* __restrict__ Ws,
                             const float* __restrict__ Wp,
                             float* __restrict__ out) {
    int r = blockIdx.x * 256 + threadIdx.x; // 0..8191
    float m = -INFINITY, s = 0.f, p = -INFINITY;
#pragma unroll
    for (int sb = 0; sb < SPLITS; ++sb) {
        float m2 = Wm[sb * N_TOT + r];
        float s2 = Ws[sb * N_TOT + r];
        float p2 = Wp[sb * N_TOT + r];
        float M = fmaxf(m, m2);
        s = s * __builtin_amdgcn_exp2f(m - M) + s2 * __builtin_amdgcn_exp2f(m2 - M);
        m = M;
        p = fmaxf(p, p2);
    }
    // aug row = [pos, neg-row]: add exp(pos) once more
    s += __builtin_amdgcn_exp2f(p - m);
    float loss = ((m + __builtin_amdgcn_logf(s)) - p) * LN2F;

#pragma unroll
    for (int off = 32; off >= 1; off >>= 1)
        loss += __shfl_down(loss, off);
    __shared__ float wsum[4];
    if ((threadIdx.x & 63) == 0) wsum[threadIdx.x >> 6] = loss;
    __syncthreads();
    if (threadIdx.x == 0) {
        float t = wsum[0] + wsum[1] + wsum[2] + wsum[3];
        atomicAdd(out, t * (1.0f / (float)N_TOT));
    }
}

extern "C" void kernel_launch(void* const* d_in, const int* in_sizes, int n_in,
                              void* d_out, int out_size, void* d_ws, size_t ws_size,
                              hipStream_t stream) {
    const float* zi = (const float*)d_in[0];
    const float* zj = (const float*)d_in[1];
    float* out = (float*)d_out;

    unsigned short* zf = (unsigned short*)d_ws;                // 2 MB
    float* Wm = (float*)((char*)d_ws + (size_t)N_TOT * DIM * 2);
    float* Ws = Wm + SPLITS * N_TOT;
    float* Wp = Ws + SPLITS * N_TOT;

    hipMemsetAsync(d_out, 0, sizeof(float), stream);
    convert_kernel<<<(N_TOT * DIM / 8) / 256, 256, 0, stream>>>(zi, zj, zf);
    ntxent_main<<<(128 * SPLITS) / 4, 256, 0, stream>>>(zf, Wm, Ws, Wp);
    merge_kernel<<<N_TOT / 256, 256, 0, stream>>>(Wm, Ws, Wp, out);
}

// Round 9
// 40.818 us; speedup vs baseline: 3.3386x; 1.0222x over previous
//
#include <hip/hip_runtime.h>
#include <hip/hip_bf16.h>

// NT-Xent loss, fused flash-LSE over sim = z z^T / T, bf16 32x32x16 MFMA.
// z pre-packed into FRAGMENT-MAJOR zf (convert kernel):
//   zf[((tile*8 + ks)*64 + l) * 8 .. +8] =
//       bf16(z[tile*32 + (l&31)][(l>>5)*8 + ks*16 .. +8] * PRESCALE)
// ROUND 9: R5-R8 were bound by the per-CU L1/TA port (~64B/cyc): every wave
// re-pulled the whole A-stream through it (1.3 MB/CU) in bursts -> convoy
// oscillation, 77% no-issue stall (R5 PMC). Fix: stage each 8KB A-tile in
// LDS ONCE PER BLOCK via global_load_lds (fragment-major layout is exactly
// the lane-linear form the DMA needs), 4x fewer global bytes; waves read
// tiles with conflict-free lane-linear ds_read_b128. Double-buffered,
// barrier-first schedule: {vmcnt(own stage t) -> s_barrier -> issue stage
// t+1 -> compute tile t}. B stays register-resident (64 rows/wave).

#define N_TOT 8192
#define B_HALF 4096
#define DIM 128
#define SPLITS 16
#define COLS_PER_SPLIT 512
#define NT 16                              // col-tiles of 32 per block
#define PRESCALE 4.5398159686f             // sqrt(log2(e)/0.07)
#define LN2F 0.6931471805599453f

typedef __attribute__((ext_vector_type(8))) short bf16x8;
typedef __attribute__((ext_vector_type(16))) float f32x16;

__device__ __forceinline__ unsigned short f2bf_rne(float f) {
    unsigned int u = __float_as_uint(f);
    u += 0x7FFFu + ((u >> 16) & 1u);
    return (unsigned short)(u >> 16);
}

__device__ __forceinline__ void gload16(const void* g, void* l) {
    __builtin_amdgcn_global_load_lds(
        (const __attribute__((address_space(1))) unsigned int*)g,
        (__attribute__((address_space(3))) unsigned int*)l, 16, 0, 0);
}

// ---- kernel 1: convert f32 z_i,z_j -> pre-scaled bf16 fragment-major zf ----
__global__ void convert_kernel(const float* __restrict__ zi,
                               const float* __restrict__ zj,
                               unsigned short* __restrict__ zf) {
    int t = blockIdx.x * 256 + threadIdx.x;   // slot 0..131071
    int l = t & 63;                           // lane slot
    int ks = (t >> 6) & 7;                    // k-step
    int tile = t >> 9;                        // 32-row tile
    int r = tile * 32 + (l & 31);
    int c = (l >> 5) * 8 + ks * 16;
    long si = (long)r * DIM + c;
    const float* src = (si < (long)B_HALF * DIM) ? (zi + si) : (zj + (si - (long)B_HALF * DIM));
    float4 v0 = *(const float4*)src;
    float4 v1 = *(const float4*)(src + 4);
    bf16x8 o;
    o[0] = (short)f2bf_rne(v0.x * PRESCALE);
    o[1] = (short)f2bf_rne(v0.y * PRESCALE);
    o[2] = (short)f2bf_rne(v0.z * PRESCALE);
    o[3] = (short)f2bf_rne(v0.w * PRESCALE);
    o[4] = (short)f2bf_rne(v1.x * PRESCALE);
    o[5] = (short)f2bf_rne(v1.y * PRESCALE);
    o[6] = (short)f2bf_rne(v1.z * PRESCALE);
    o[7] = (short)f2bf_rne(v1.w * PRESCALE);
    *(bf16x8*)(zf + (size_t)t * 8) = o;
}

// consume one 32x32 result tile (acc) for rows [rbase, rbase+32) at
// stream-col base cb into (mv, sv, pv). Branchless deferred-max LSE.
#define CONSUME(accv, mv, sv, pv, rbase, cbv)                                  \
    do {                                                                       \
        const int cb_ = (cbv);                                                 \
        const int rb_ = (rbase);                                               \
        if (cb_ == rb_ || cb_ == (rb_ ^ B_HALF)) {                             \
            const int j_ = rb_ + l5;                                           \
            _Pragma("unroll")                                                  \
            for (int q = 0; q < 16; ++q) {                                     \
                int iq = cb_ + (q & 3) + 8 * (q >> 2) + 4 * hb;                \
                if (iq == j_) accv[q] = -INFINITY;                             \
                else if (iq == (j_ ^ B_HALF)) pv = accv[q];                    \
            }                                                                  \
        }                                                                      \
        float x0 = fmaxf(fmaxf(accv[0], accv[1]), accv[2]);                    \
        float x1 = fmaxf(fmaxf(accv[3], accv[4]), accv[5]);                    \
        float x2 = fmaxf(fmaxf(accv[6], accv[7]), accv[8]);                    \
        float x3 = fmaxf(fmaxf(accv[9], accv[10]), accv[11]);                  \
        float x4 = fmaxf(fmaxf(accv[12], accv[13]), accv[14]);                 \
        float y0 = fmaxf(fmaxf(x0, x1), x2);                                   \
        float y1 = fmaxf(fmaxf(x3, x4), accv[15]);                             \
        float mn = fmaxf(fmaxf(y0, y1), mv);                                   \
        float rr = __builtin_amdgcn_exp2f(mv - mn); /* exp2(0)=1 no-op */      \
        float e0 = __builtin_amdgcn_exp2f(accv[0] - mn);                       \
        float e1 = __builtin_amdgcn_exp2f(accv[1] - mn);                       \
        float e2 = __builtin_amdgcn_exp2f(accv[2] - mn);                       \
        float e3 = __builtin_amdgcn_exp2f(accv[3] - mn);                       \
        float e4 = __builtin_amdgcn_exp2f(accv[4] - mn);                       \
        float e5 = __builtin_amdgcn_exp2f(accv[5] - mn);                       \
        float e6 = __builtin_amdgcn_exp2f(accv[6] - mn);                       \
        float e7 = __builtin_amdgcn_exp2f(accv[7] - mn);                       \
        float e8 = __builtin_amdgcn_exp2f(accv[8] - mn);                       \
        float e9 = __builtin_amdgcn_exp2f(accv[9] - mn);                       \
        float ea = __builtin_amdgcn_exp2f(accv[10] - mn);                      \
        float eb = __builtin_amdgcn_exp2f(accv[11] - mn);                      \
        float ec = __builtin_amdgcn_exp2f(accv[12] - mn);                      \
        float ed = __builtin_amdgcn_exp2f(accv[13] - mn);                      \
        float ee = __builtin_amdgcn_exp2f(accv[14] - mn);                      \
        float ef = __builtin_amdgcn_exp2f(accv[15] - mn);                      \
        float t0 = (e0 + e1) + (e2 + e3);                                      \
        float t1 = (e4 + e5) + (e6 + e7);                                      \
        float t2 = (e8 + e9) + (ea + eb);                                      \
        float t3 = (ec + ed) + (ee + ef);                                      \
        sv = sv * rr + ((t0 + t1) + (t2 + t3));                                \
        mv = mn;                                                               \
    } while (0)

#define ZERO16(accv)                                                           \
    do { _Pragma("unroll") for (int q = 0; q < 16; ++q) accv[q] = 0.f; } while (0)

// wave w stages fragments 2w, 2w+1 of col-tile (tIdx0 + t) into lds[b]
#define STAGE(t, b)                                                            \
    do {                                                                       \
        const unsigned short* s_ =                                             \
            zf + ((size_t)(tIdx0 + (t)) * 8 + 2 * w) * 512 + l * 8;            \
        gload16(s_, &lds[b][(2 * w) * 64]);                                    \
        gload16(s_ + 512, &lds[b][(2 * w + 1) * 64]);                          \
    } while (0)

// ---- kernel 2: main fused GEMM + online LSE (LDS-staged A, reg B) ----
// grid: 32 row-blocks (256 rows) x 16 col-splits (512 cols) = 512 blocks,
// 256 threads (4 waves); wave w owns rows rb*256 + w*64 .. +64.
__global__ __launch_bounds__(256, 2) void ntxent_main(
        const unsigned short* __restrict__ zf,
        float* __restrict__ Wm, float* __restrict__ Ws, float* __restrict__ Wp) {
    __shared__ bf16x8 lds[2][512];  // 2 x 8KB col-tile buffers

    const int bid = blockIdx.x;
    const int rb = bid / SPLITS;
    const int sp = bid % SPLITS;
    const int tid = threadIdx.x;
    const int w = tid >> 6;
    const int l = tid & 63;
    const int l5 = l & 31;
    const int hb = l >> 5;

    const int rowbase = rb * 256 + w * 64;
    const int cb0 = sp * COLS_PER_SPLIT;
    const int tIdx0 = cb0 >> 5;

    // B fragments: two 32-row tile-sets, coalesced 1KB loads from zf
    const unsigned short* bp = zf + (size_t)(rowbase >> 5) * 4096 + l * 8;
    bf16x8 b00 = *(const bf16x8*)(bp + 0 * 512);
    bf16x8 b01 = *(const bf16x8*)(bp + 1 * 512);
    bf16x8 b02 = *(const bf16x8*)(bp + 2 * 512);
    bf16x8 b03 = *(const bf16x8*)(bp + 3 * 512);
    bf16x8 b04 = *(const bf16x8*)(bp + 4 * 512);
    bf16x8 b05 = *(const bf16x8*)(bp + 5 * 512);
    bf16x8 b06 = *(const bf16x8*)(bp + 6 * 512);
    bf16x8 b07 = *(const bf16x8*)(bp + 7 * 512);
    const unsigned short* bq = bp + 4096;
    bf16x8 b10 = *(const bf16x8*)(bq + 0 * 512);
    bf16x8 b11 = *(const bf16x8*)(bq + 1 * 512);
    bf16x8 b12 = *(const bf16x8*)(bq + 2 * 512);
    bf16x8 b13 = *(const bf16x8*)(bq + 3 * 512);
    bf16x8 b14 = *(const bf16x8*)(bq + 4 * 512);
    bf16x8 b15 = *(const bf16x8*)(bq + 5 * 512);
    bf16x8 b16 = *(const bf16x8*)(bq + 6 * 512);
    bf16x8 b17 = *(const bf16x8*)(bq + 7 * 512);

    float m0 = -INFINITY, s0 = 0.f, p0 = -INFINITY;
    float m1 = -INFINITY, s1 = 0.f, p1 = -INFINITY;
    f32x16 accA, accB;

    STAGE(0, 0);   // prologue

#pragma unroll 2
    for (int t = 0; t < NT; ++t) {
        // own stage(t) loads are the newest VMEM -> vmcnt(0) completes them
        asm volatile("s_waitcnt vmcnt(0)" ::: "memory");
        __builtin_amdgcn_s_barrier();   // all waves: stage(t) done; buf[(t+1)&1] free
        __builtin_amdgcn_sched_barrier(0);
        if (t + 1 < NT) STAGE(t + 1, (t + 1) & 1);

        const bf16x8* Lb = lds[t & 1];
        bf16x8 f0 = Lb[0 * 64 + l];
        bf16x8 f1 = Lb[1 * 64 + l];
        bf16x8 f2 = Lb[2 * 64 + l];
        bf16x8 f3 = Lb[3 * 64 + l];
        bf16x8 f4 = Lb[4 * 64 + l];
        bf16x8 f5 = Lb[5 * 64 + l];
        bf16x8 f6 = Lb[6 * 64 + l];
        bf16x8 f7 = Lb[7 * 64 + l];

        ZERO16(accA); ZERO16(accB);
        accA = __builtin_amdgcn_mfma_f32_32x32x16_bf16(f0, b00, accA, 0, 0, 0);
        accB = __builtin_amdgcn_mfma_f32_32x32x16_bf16(f0, b10, accB, 0, 0, 0);
        accA = __builtin_amdgcn_mfma_f32_32x32x16_bf16(f1, b01, accA, 0, 0, 0);
        accB = __builtin_amdgcn_mfma_f32_32x32x16_bf16(f1, b11, accB, 0, 0, 0);
        accA = __builtin_amdgcn_mfma_f32_32x32x16_bf16(f2, b02, accA, 0, 0, 0);
        accB = __builtin_amdgcn_mfma_f32_32x32x16_bf16(f2, b12, accB, 0, 0, 0);
        accA = __builtin_amdgcn_mfma_f32_32x32x16_bf16(f3, b03, accA, 0, 0, 0);
        accB = __builtin_amdgcn_mfma_f32_32x32x16_bf16(f3, b13, accB, 0, 0, 0);
        accA = __builtin_amdgcn_mfma_f32_32x32x16_bf16(f4, b04, accA, 0, 0, 0);
        accB = __builtin_amdgcn_mfma_f32_32x32x16_bf16(f4, b14, accB, 0, 0, 0);
        accA = __builtin_amdgcn_mfma_f32_32x32x16_bf16(f5, b05, accA, 0, 0, 0);
        accB = __builtin_amdgcn_mfma_f32_32x32x16_bf16(f5, b15, accB, 0, 0, 0);
        accA = __builtin_amdgcn_mfma_f32_32x32x16_bf16(f6, b06, accA, 0, 0, 0);
        accB = __builtin_amdgcn_mfma_f32_32x32x16_bf16(f6, b16, accB, 0, 0, 0);
        accA = __builtin_amdgcn_mfma_f32_32x32x16_bf16(f7, b07, accA, 0, 0, 0);
        accB = __builtin_amdgcn_mfma_f32_32x32x16_bf16(f7, b17, accB, 0, 0, 0);

        const int cbv = cb0 + t * 32;
        CONSUME(accA, m0, s0, p0, rowbase, cbv);
        CONSUME(accB, m1, s1, p1, rowbase + 32, cbv);
    }

    // lanes l and l^32 hold the same row over disjoint k-halves...: merge
    {
        float m2 = __shfl_xor(m0, 32);
        float s2 = __shfl_xor(s0, 32);
        float q2 = __shfl_xor(p0, 32);
        float M = fmaxf(m0, m2);
        s0 = s0 * __builtin_amdgcn_exp2f(m0 - M) + s2 * __builtin_amdgcn_exp2f(m2 - M);
        p0 = fmaxf(p0, q2);
        if (l < 32) {
            int r = rowbase + l;
            Wm[sp * N_TOT + r] = M;
            Ws[sp * N_TOT + r] = s0;
            Wp[sp * N_TOT + r] = p0;
        }
    }
    {
        float m2 = __shfl_xor(m1, 32);
        float s2 = __shfl_xor(s1, 32);
        float q2 = __shfl_xor(p1, 32);
        float M = fmaxf(m1, m2);
        s1 = s1 * __builtin_amdgcn_exp2f(m1 - M) + s2 * __builtin_amdgcn_exp2f(m2 - M);
        p1 = fmaxf(p1, q2);
        if (l < 32) {
            int r = rowbase + 32 + l;
            Wm[sp * N_TOT + r] = M;
            Ws[sp * N_TOT + r] = s1;
            Wp[sp * N_TOT + r] = p1;
        }
    }
}

// ---- kernel 3: merge splits, compute loss, reduce ----
__global__ void merge_kernel(const float* __restrict__ Wm,
                             const float* __restrict__ Ws,
                             const float* __restrict__ Wp,
                             float* __restrict__ out) {
    int r = blockIdx.x * 256 + threadIdx.x; // 0..8191
    float m = -INFINITY, s = 0.f, p = -INFINITY;
#pragma unroll
    for (int sb = 0; sb < SPLITS; ++sb) {
        float m2 = Wm[sb * N_TOT + r];
        float s2 = Ws[sb * N_TOT + r];
        float p2 = Wp[sb * N_TOT + r];
        float M = fmaxf(m, m2);
        s = s * __builtin_amdgcn_exp2f(m - M) + s2 * __builtin_amdgcn_exp2f(m2 - M);
        m = M;
        p = fmaxf(p, p2);
    }
    // aug row = [pos, neg-row]: add exp(pos) once more
    s += __builtin_amdgcn_exp2f(p - m);
    float loss = ((m + __builtin_amdgcn_logf(s)) - p) * LN2F;

#pragma unroll
    for (int off = 32; off >= 1; off >>= 1)
        loss += __shfl_down(loss, off);
    __shared__ float wsum[4];
    if ((threadIdx.x & 63) == 0) wsum[threadIdx.x >> 6] = loss;
    __syncthreads();
    if (threadIdx.x == 0) {
        float t = wsum[0] + wsum[1] + wsum[2] + wsum[3];
        atomicAdd(out, t * (1.0f / (float)N_TOT));
    }
}

extern "C" void kernel_launch(void* const* d_in, const int* in_sizes, int n_in,
                              void* d_out, int out_size, void* d_ws, size_t ws_size,
                              hipStream_t stream) {
    const float* zi = (const float*)d_in[0];
    const float* zj = (const float*)d_in[1];
    float* out = (float*)d_out;

    unsigned short* zf = (unsigned short*)d_ws;                // 2 MB
    float* Wm = (float*)((char*)d_ws + (size_t)N_TOT * DIM * 2);
    float* Ws = Wm + SPLITS * N_TOT;
    float* Wp = Ws + SPLITS * N_TOT;

    hipMemsetAsync(d_out, 0, sizeof(float), stream);
    convert_kernel<<<(N_TOT * DIM / 8) / 256, 256, 0, stream>>>(zi, zj, zf);
    ntxent_main<<<32 * SPLITS, 256, 0, stream>>>(zf, Wm, Ws, Wp);
    merge_kernel<<<N_TOT / 256, 256, 0, stream>>>(Wm, Ws, Wp, out);
}